// Round 1
// baseline (1056.131 us; speedup 1.0000x reference)
//
#include <hip/hip_runtime.h>
#include <math.h>

#define Bsz   2
#define Lseq  4096
#define DMdim 256
#define DOUTd 128
#define DSTd  16
#define DId   512
#define DTRd  16
#define CS    64
#define NCh   64
#define NROWS (Bsz*Lseq)   // 8192

__device__ __forceinline__ float siluf(float x) { return x / (1.f + __expf(-x)); }
__device__ __forceinline__ float softplusf(float x) {
  return fmaxf(x, 0.f) + log1pf(__expf(-fabsf(x)));
}

// res = (first ? x : res + h); hn = LN(res)*w + b
__global__ __launch_bounds__(256) void resid_ln_kernel(
    const float* __restrict__ addsrc, float* __restrict__ res, float* __restrict__ hn,
    const float* __restrict__ w, const float* __restrict__ b, int first)
{
  int row = blockIdx.x;
  int t = threadIdx.x;
  size_t o = (size_t)row * DMdim + t;
  float v = first ? addsrc[o] : (res[o] + addsrc[o]);
  res[o] = v;
  float s1 = v, s2 = v * v;
  #pragma unroll
  for (int m = 32; m >= 1; m >>= 1) {
    s1 += __shfl_xor(s1, m, 64);
    s2 += __shfl_xor(s2, m, 64);
  }
  __shared__ float w1[4], w2[4];
  int wid = t >> 6, ln = t & 63;
  if (ln == 0) { w1[wid] = s1; w2[wid] = s2; }
  __syncthreads();
  float S1 = w1[0] + w1[1] + w1[2] + w1[3];
  float S2 = w2[0] + w2[1] + w2[2] + w2[3];
  float mean = S1 * (1.f / DMdim);
  float var  = S2 * (1.f / DMdim) - mean * mean;
  float r = rsqrtf(var + 1e-5f);
  hn[o] = (v - mean) * r * w[t] + b[t];
}

// C[m,n] = sum_k A[m,k]*W[n,k].  A:(M,K) row-major, W:(N,K) row-major, C:(M,N).
__global__ __launch_bounds__(256) void gemm_nt_kernel(
    const float* __restrict__ A, const float* __restrict__ W, float* __restrict__ C,
    int M, int N, int K)
{
  __shared__ float As[16][68];   // [k][m], row stride 68 floats (rows stay 16B-aligned)
  __shared__ float Ws[16][68];   // [k][n]
  int tid = threadIdx.x;
  int bm = blockIdx.x * 64;
  int bn = blockIdx.y * 64;
  int tx = tid & 15, ty = tid >> 4;
  int lr = tid >> 2;             // 0..63
  int lk = (tid & 3) << 2;       // 0,4,8,12
  float acc[4][4];
  #pragma unroll
  for (int i = 0; i < 4; i++)
    #pragma unroll
    for (int j = 0; j < 4; j++) acc[i][j] = 0.f;
  const float* Ap = A + (size_t)(bm + lr) * K + lk;
  int wrow = bn + lr;
  const float* Wp = W + (size_t)wrow * K + lk;
  bool wok = (wrow < N);
  for (int k0 = 0; k0 < K; k0 += 16) {
    float4 av = *(const float4*)(Ap + k0);
    float4 wv = make_float4(0.f, 0.f, 0.f, 0.f);
    if (wok) wv = *(const float4*)(Wp + k0);
    As[lk+0][lr] = av.x; As[lk+1][lr] = av.y; As[lk+2][lr] = av.z; As[lk+3][lr] = av.w;
    Ws[lk+0][lr] = wv.x; Ws[lk+1][lr] = wv.y; Ws[lk+2][lr] = wv.z; Ws[lk+3][lr] = wv.w;
    __syncthreads();
    #pragma unroll
    for (int kk = 0; kk < 16; kk++) {
      float4 a  = *(const float4*)&As[kk][ty << 2];
      float4 w4 = *(const float4*)&Ws[kk][tx << 2];
      acc[0][0] = fmaf(a.x, w4.x, acc[0][0]);
      acc[0][1] = fmaf(a.x, w4.y, acc[0][1]);
      acc[0][2] = fmaf(a.x, w4.z, acc[0][2]);
      acc[0][3] = fmaf(a.x, w4.w, acc[0][3]);
      acc[1][0] = fmaf(a.y, w4.x, acc[1][0]);
      acc[1][1] = fmaf(a.y, w4.y, acc[1][1]);
      acc[1][2] = fmaf(a.y, w4.z, acc[1][2]);
      acc[1][3] = fmaf(a.y, w4.w, acc[1][3]);
      acc[2][0] = fmaf(a.z, w4.x, acc[2][0]);
      acc[2][1] = fmaf(a.z, w4.y, acc[2][1]);
      acc[2][2] = fmaf(a.z, w4.z, acc[2][2]);
      acc[2][3] = fmaf(a.z, w4.w, acc[2][3]);
      acc[3][0] = fmaf(a.w, w4.x, acc[3][0]);
      acc[3][1] = fmaf(a.w, w4.y, acc[3][1]);
      acc[3][2] = fmaf(a.w, w4.z, acc[3][2]);
      acc[3][3] = fmaf(a.w, w4.w, acc[3][3]);
    }
    __syncthreads();
  }
  #pragma unroll
  for (int i = 0; i < 4; i++) {
    int m = bm + (ty << 2) + i;
    #pragma unroll
    for (int j = 0; j < 4; j++) {
      int n = bn + (tx << 2) + j;
      if (n < N) C[(size_t)m * N + n] = acc[i][j];
    }
  }
}

// uc[b,l,d] = silu(sum_k convw[d,k]*u[b,l-2+k,d] + convb[d]);  u = xz[...,:DI]
__global__ __launch_bounds__(256) void conv_silu_kernel(
    const float* __restrict__ xz, const float* __restrict__ cw,
    const float* __restrict__ cb, float* __restrict__ uc)
{
  int idx = blockIdx.x * 256 + threadIdx.x;   // B*L*DI
  int d  = idx & (DId - 1);
  int bl = idx >> 9;
  int l  = bl & (Lseq - 1);
  float w0 = cw[d*3+0], w1 = cw[d*3+1], w2 = cw[d*3+2];
  float acc = cb[d];
  acc = fmaf(xz[(size_t)bl * (2*DId) + d], w2, acc);
  if (l >= 1) acc = fmaf(xz[(size_t)(bl-1) * (2*DId) + d], w1, acc);
  if (l >= 2) acc = fmaf(xz[(size_t)(bl-2) * (2*DId) + d], w0, acc);
  uc[idx] = siluf(acc);
}

// dtf[b,l,d] = softplus(sum_r xdbl[b,l,r]*dtw[d,r] + dtb[d])
__global__ __launch_bounds__(256) void dt_kernel(
    const float* __restrict__ xdbl, const float* __restrict__ dtw,
    const float* __restrict__ dtb, float* __restrict__ dtf)
{
  int idx = blockIdx.x * 256 + threadIdx.x;   // B*L*DI
  int d  = idx & (DId - 1);
  int bl = idx >> 9;
  const float* dp = xdbl + (size_t)bl * 48;
  float a = dtb[d];
  #pragma unroll
  for (int r = 0; r < DTRd; r++) a = fmaf(dp[r], dtw[d*DTRd + r], a);
  dtf[idx] = softplusf(a);
}

// pass1: per (b,chunk,d,n) local scan with h0=0; store end state + total decay
__global__ __launch_bounds__(256) void scan1_kernel(
    const float* __restrict__ dtf, const float* __restrict__ uc,
    const float* __restrict__ xdbl, const float* __restrict__ A_log,
    float* __restrict__ hloc, float* __restrict__ Pst)
{
  int tid = threadIdx.x;
  int n = tid & 15, g = tid >> 4;
  int bx = blockIdx.x;
  int dblk = bx & 31, c = (bx >> 5) & 63, b = bx >> 11;
  int d = dblk * 16 + g;
  float A = -__expf(A_log[d * DSTd + n]);
  float h = 0.f, sdt = 0.f;
  size_t base = (size_t)b * Lseq + c * CS;
  for (int t = 0; t < CS; t++) {
    size_t rowi = base + t;
    float dt = dtf[rowi * DId + d];
    float u  = uc [rowi * DId + d];
    float Bn = xdbl[rowi * 48 + DTRd + n];
    h = fmaf(__expf(dt * A), h, dt * u * Bn);
    sdt += dt;
  }
  size_t so = (((size_t)(b * NCh + c) * DId) + d) * DSTd + n;
  hloc[so] = h;
  Pst[so]  = __expf(A * sdt);
}

// pass2: sequential scan over chunks; store incoming state per chunk
__global__ __launch_bounds__(256) void scan2_kernel(
    const float* __restrict__ hloc, const float* __restrict__ Pst,
    float* __restrict__ Hinit)
{
  int idx = blockIdx.x * 256 + threadIdx.x;  // B*DI*DST = 16384
  int dn = idx & (DId * DSTd - 1);
  int b  = idx >> 13;
  float H = 0.f;
  for (int c = 0; c < NCh; c++) {
    size_t o = ((size_t)(b * NCh + c)) * (DId * DSTd) + dn;
    Hinit[o] = H;
    H = fmaf(Pst[o], H, hloc[o]);
  }
}

// pass3: rerun chunk scan with correct h0; y = C·h; write (y+u*D)*silu(z) in place over uc
__global__ __launch_bounds__(256) void scan3_kernel(
    const float* __restrict__ dtf, float* __restrict__ uc,
    const float* __restrict__ xdbl, const float* __restrict__ xz,
    const float* __restrict__ A_log, const float* __restrict__ Dv,
    const float* __restrict__ Hinit)
{
  int tid = threadIdx.x;
  int n = tid & 15, g = tid >> 4;
  int bx = blockIdx.x;
  int dblk = bx & 31, c = (bx >> 5) & 63, b = bx >> 11;
  int d = dblk * 16 + g;
  float A = -__expf(A_log[d * DSTd + n]);
  size_t so = (((size_t)(b * NCh + c) * DId) + d) * DSTd + n;
  float h = Hinit[so];
  float Dd = Dv[d];
  size_t base = (size_t)b * Lseq + c * CS;
  for (int t = 0; t < CS; t++) {
    size_t rowi = base + t;
    float dt = dtf[rowi * DId + d];
    float u  = uc [rowi * DId + d];
    float Bn = xdbl[rowi * 48 + DTRd + n];
    float Cn = xdbl[rowi * 48 + DTRd + DSTd + n];
    h = fmaf(__expf(dt * A), h, dt * u * Bn);
    float p = h * Cn;
    p += __shfl_xor(p, 1, 16);
    p += __shfl_xor(p, 2, 16);
    p += __shfl_xor(p, 4, 16);
    p += __shfl_xor(p, 8, 16);
    if (n == 0) {
      float z = xz[rowi * (2*DId) + DId + d];
      uc[rowi * DId + d] = (p + u * Dd) * siluf(z);  // all lanes read u above (wave lockstep) before this write
    }
  }
}

extern "C" void kernel_launch(void* const* d_in, const int* in_sizes, int n_in,
                              void* d_out, int out_size, void* d_ws, size_t ws_size,
                              hipStream_t stream)
{
  const float* x          = (const float*)d_in[0];
  const float* midW_in    = (const float*)d_in[1];
  const float* midW_convw = (const float*)d_in[2];
  const float* midW_convb = (const float*)d_in[3];
  const float* midW_x     = (const float*)d_in[4];
  const float* midW_dtw   = (const float*)d_in[5];
  const float* midW_dtb   = (const float*)d_in[6];
  const float* midA_log   = (const float*)d_in[7];
  const float* midD       = (const float*)d_in[8];
  const float* midW_out   = (const float*)d_in[9];
  const float* midLNw     = (const float*)d_in[10];
  const float* midLNb     = (const float*)d_in[11];
  const float* finW_in    = (const float*)d_in[12];
  const float* finW_convw = (const float*)d_in[13];
  const float* finW_convb = (const float*)d_in[14];
  const float* finW_x     = (const float*)d_in[15];
  const float* finW_dtw   = (const float*)d_in[16];
  const float* finW_dtb   = (const float*)d_in[17];
  const float* finA_log   = (const float*)d_in[18];
  const float* finD       = (const float*)d_in[19];
  const float* finW_out   = (const float*)d_in[20];
  const float* finLNw     = (const float*)d_in[21];
  const float* finLNb     = (const float*)d_in[22];

  // workspace layout (floats) — total ~106.4 MB
  float* ws    = (float*)d_ws;
  float* res   = ws;                    // 2,097,152
  float* hn    = res   + 2097152;       // 2,097,152
  float* hbuf  = hn    + 2097152;       // 2,097,152
  float* xz    = hbuf  + 2097152;       // 8,388,608
  float* uc    = xz    + 8388608;       // 4,194,304
  float* xdbl  = uc    + 4194304;       // 393,216
  float* dtf   = xdbl  + 393216;        // 4,194,304
  float* hloc  = dtf   + 4194304;       // 1,048,576
  float* Pst   = hloc  + 1048576;       // 1,048,576
  float* Hinit = Pst   + 1048576;       // 1,048,576

  for (int blk = 0; blk < 3; blk++) {
    const float *Win, *convw, *convb, *Wx, *dtw, *dtb, *Alog, *Dv, *Wout, *lnw, *lnb;
    int Nout;
    if (blk < 2) {
      Win   = midW_in    + (size_t)blk * 2*DId*DMdim;
      convw = midW_convw + (size_t)blk * DId*3;
      convb = midW_convb + (size_t)blk * DId;
      Wx    = midW_x     + (size_t)blk * 48*DId;
      dtw   = midW_dtw   + (size_t)blk * DId*DTRd;
      dtb   = midW_dtb   + (size_t)blk * DId;
      Alog  = midA_log   + (size_t)blk * DId*DSTd;
      Dv    = midD       + (size_t)blk * DId;
      Wout  = midW_out   + (size_t)blk * DMdim*DId;
      lnw   = midLNw     + (size_t)blk * DMdim;
      lnb   = midLNb     + (size_t)blk * DMdim;
      Nout  = DMdim;
    } else {
      Win = finW_in; convw = finW_convw; convb = finW_convb; Wx = finW_x;
      dtw = finW_dtw; dtb = finW_dtb; Alog = finA_log; Dv = finD;
      Wout = finW_out; lnw = finLNw; lnb = finLNb;
      Nout = DOUTd;
    }
    const float* addsrc = (blk == 0) ? x : hbuf;
    resid_ln_kernel<<<NROWS, 256, 0, stream>>>(addsrc, res, hn, lnw, lnb, blk == 0 ? 1 : 0);

    dim3 g1(NROWS/64, (2*DId)/64);
    gemm_nt_kernel<<<g1, 256, 0, stream>>>(hn, Win, xz, NROWS, 2*DId, DMdim);

    conv_silu_kernel<<<(NROWS*DId)/256, 256, 0, stream>>>(xz, convw, convb, uc);

    dim3 g2(NROWS/64, 1);
    gemm_nt_kernel<<<g2, 256, 0, stream>>>(uc, Wx, xdbl, NROWS, 48, DId);

    dt_kernel<<<(NROWS*DId)/256, 256, 0, stream>>>(xdbl, dtw, dtb, dtf);

    scan1_kernel<<<4096, 256, 0, stream>>>(dtf, uc, xdbl, Alog, hloc, Pst);
    scan2_kernel<<<64, 256, 0, stream>>>(hloc, Pst, Hinit);
    scan3_kernel<<<4096, 256, 0, stream>>>(dtf, uc, xdbl, xz, Alog, Dv, Hinit);

    float* Cout = (blk == 2) ? (float*)d_out : hbuf;
    dim3 g3(NROWS/64, Nout/64);
    gemm_nt_kernel<<<g3, 256, 0, stream>>>(uc, Wout, Cout, NROWS, Nout, DId);
  }
}

// Round 2
// 818.957 us; speedup vs baseline: 1.2896x; 1.2896x over previous
//
#include <hip/hip_runtime.h>
#include <math.h>

#define Bsz   2
#define Lseq  4096
#define DMdim 256
#define DOUTd 128
#define DSTd  16
#define DId   512
#define DTRd  16
#define CS    32
#define NCh   128
#define NROWS (Bsz*Lseq)   // 8192

__device__ __forceinline__ float siluf(float x) { return x / (1.f + __expf(-x)); }
__device__ __forceinline__ float softplusf(float x) {
  return fmaxf(x, 0.f) + log1pf(__expf(-fabsf(x)));
}

// res = (first ? x : res + h); hn = LN(res)*w + b
__global__ __launch_bounds__(256) void resid_ln_kernel(
    const float* __restrict__ addsrc, float* __restrict__ res, float* __restrict__ hn,
    const float* __restrict__ w, const float* __restrict__ b, int first)
{
  int row = blockIdx.x;
  int t = threadIdx.x;
  size_t o = (size_t)row * DMdim + t;
  float v = first ? addsrc[o] : (res[o] + addsrc[o]);
  res[o] = v;
  float s1 = v, s2 = v * v;
  #pragma unroll
  for (int m = 32; m >= 1; m >>= 1) {
    s1 += __shfl_xor(s1, m, 64);
    s2 += __shfl_xor(s2, m, 64);
  }
  __shared__ float w1[4], w2[4];
  int wid = t >> 6, ln = t & 63;
  if (ln == 0) { w1[wid] = s1; w2[wid] = s2; }
  __syncthreads();
  float S1 = w1[0] + w1[1] + w1[2] + w1[3];
  float S2 = w2[0] + w2[1] + w2[2] + w2[3];
  float mean = S1 * (1.f / DMdim);
  float var  = S2 * (1.f / DMdim) - mean * mean;
  float r = rsqrtf(var + 1e-5f);
  hn[o] = (v - mean) * r * w[t] + b[t];
}

// C[m,n] = sum_k A[m,k]*W[n,k].  A:(M,K) row-major, W:(N,K) row-major, C:(M,N).
__global__ __launch_bounds__(256) void gemm_nt_kernel(
    const float* __restrict__ A, const float* __restrict__ W, float* __restrict__ C,
    int M, int N, int K)
{
  __shared__ float As[16][68];
  __shared__ float Ws[16][68];
  int tid = threadIdx.x;
  int bm = blockIdx.x * 64;
  int bn = blockIdx.y * 64;
  int tx = tid & 15, ty = tid >> 4;
  int lr = tid >> 2;
  int lk = (tid & 3) << 2;
  float acc[4][4];
  #pragma unroll
  for (int i = 0; i < 4; i++)
    #pragma unroll
    for (int j = 0; j < 4; j++) acc[i][j] = 0.f;
  const float* Ap = A + (size_t)(bm + lr) * K + lk;
  int wrow = bn + lr;
  const float* Wp = W + (size_t)wrow * K + lk;
  bool wok = (wrow < N);
  for (int k0 = 0; k0 < K; k0 += 16) {
    float4 av = *(const float4*)(Ap + k0);
    float4 wv = make_float4(0.f, 0.f, 0.f, 0.f);
    if (wok) wv = *(const float4*)(Wp + k0);
    As[lk+0][lr] = av.x; As[lk+1][lr] = av.y; As[lk+2][lr] = av.z; As[lk+3][lr] = av.w;
    Ws[lk+0][lr] = wv.x; Ws[lk+1][lr] = wv.y; Ws[lk+2][lr] = wv.z; Ws[lk+3][lr] = wv.w;
    __syncthreads();
    #pragma unroll
    for (int kk = 0; kk < 16; kk++) {
      float4 a  = *(const float4*)&As[kk][ty << 2];
      float4 w4 = *(const float4*)&Ws[kk][tx << 2];
      acc[0][0] = fmaf(a.x, w4.x, acc[0][0]);
      acc[0][1] = fmaf(a.x, w4.y, acc[0][1]);
      acc[0][2] = fmaf(a.x, w4.z, acc[0][2]);
      acc[0][3] = fmaf(a.x, w4.w, acc[0][3]);
      acc[1][0] = fmaf(a.y, w4.x, acc[1][0]);
      acc[1][1] = fmaf(a.y, w4.y, acc[1][1]);
      acc[1][2] = fmaf(a.y, w4.z, acc[1][2]);
      acc[1][3] = fmaf(a.y, w4.w, acc[1][3]);
      acc[2][0] = fmaf(a.z, w4.x, acc[2][0]);
      acc[2][1] = fmaf(a.z, w4.y, acc[2][1]);
      acc[2][2] = fmaf(a.z, w4.z, acc[2][2]);
      acc[2][3] = fmaf(a.z, w4.w, acc[2][3]);
      acc[3][0] = fmaf(a.w, w4.x, acc[3][0]);
      acc[3][1] = fmaf(a.w, w4.y, acc[3][1]);
      acc[3][2] = fmaf(a.w, w4.z, acc[3][2]);
      acc[3][3] = fmaf(a.w, w4.w, acc[3][3]);
    }
    __syncthreads();
  }
  #pragma unroll
  for (int i = 0; i < 4; i++) {
    int m = bm + (ty << 2) + i;
    #pragma unroll
    for (int j = 0; j < 4; j++) {
      int n = bn + (tx << 2) + j;
      if (n < N) C[(size_t)m * N + n] = acc[i][j];
    }
  }
}

// uc[b,l,d] = silu(conv(u)) ; u = xz[...,:DI]
__global__ __launch_bounds__(256) void conv_silu_kernel(
    const float* __restrict__ xz, const float* __restrict__ cw,
    const float* __restrict__ cb, float* __restrict__ uc)
{
  int idx = blockIdx.x * 256 + threadIdx.x;
  int d  = idx & (DId - 1);
  int bl = idx >> 9;
  int l  = bl & (Lseq - 1);
  float w0 = cw[d*3+0], w1 = cw[d*3+1], w2 = cw[d*3+2];
  float acc = cb[d];
  acc = fmaf(xz[(size_t)bl * (2*DId) + d], w2, acc);
  if (l >= 1) acc = fmaf(xz[(size_t)(bl-1) * (2*DId) + d], w1, acc);
  if (l >= 2) acc = fmaf(xz[(size_t)(bl-2) * (2*DId) + d], w0, acc);
  uc[idx] = siluf(acc);
}

// dtf[b,l,d] = softplus(xdbl[b,l,:16] . dtw[d,:] + dtb[d])
__global__ __launch_bounds__(256) void dt_kernel(
    const float* __restrict__ xdbl, const float* __restrict__ dtw,
    const float* __restrict__ dtb, float* __restrict__ dtf)
{
  int idx = blockIdx.x * 256 + threadIdx.x;
  int d  = idx & (DId - 1);
  int bl = idx >> 9;
  const float* dp = xdbl + (size_t)bl * 48;
  float a = dtb[d];
  #pragma unroll
  for (int r = 0; r < DTRd; r++) a = fmaf(dp[r], dtw[d*DTRd + r], a);
  dtf[idx] = softplusf(a);
}

// pass1: one thread per (b,chunk,d); h[16] in registers; local scan with h0=0.
// grid: Bsz * NCh * 2 blocks of 256 (d = half*256 + tid)
__global__ __launch_bounds__(256) void scan1_kernel(
    const float* __restrict__ dtf, const float* __restrict__ uc,
    const float* __restrict__ xdbl, const float* __restrict__ A_log,
    float* __restrict__ hloc, float* __restrict__ Pst)
{
  __shared__ float Bsh[CS][16];
  int tid = threadIdx.x;
  int bx = blockIdx.x;
  int dh = bx & 1, c = (bx >> 1) & (NCh - 1), b = bx >> 8;
  int d = dh * 256 + tid;
  size_t base = (size_t)b * Lseq + (size_t)c * CS;
  for (int i = tid; i < CS * 16; i += 256) {
    int t = i >> 4, n = i & 15;
    Bsh[t][n] = xdbl[(base + t) * 48 + DTRd + n];
  }
  float A[16];
  #pragma unroll
  for (int n = 0; n < 16; n++) A[n] = -__expf(A_log[d * 16 + n]);
  __syncthreads();
  float h[16];
  #pragma unroll
  for (int n = 0; n < 16; n++) h[n] = 0.f;
  float sdt = 0.f;
  #pragma unroll 2
  for (int t = 0; t < CS; t++) {
    size_t row = base + t;
    float dt = dtf[row * DId + d];
    float u  = uc [row * DId + d];
    float du = dt * u;
    sdt += dt;
    #pragma unroll
    for (int n = 0; n < 16; n++) {
      float dA = __expf(dt * A[n]);
      h[n] = fmaf(dA, h[n], du * Bsh[t][n]);
    }
  }
  size_t so = (((size_t)(b * NCh + c) * DId) + d) * 16;
  #pragma unroll
  for (int n = 0; n < 16; n++) {
    hloc[so + n] = h[n];
    Pst [so + n] = __expf(sdt * A[n]);
  }
}

// pass2: sequential scan over chunks; store incoming state per chunk
__global__ __launch_bounds__(256) void scan2_kernel(
    const float* __restrict__ hloc, const float* __restrict__ Pst,
    float* __restrict__ Hinit)
{
  int idx = blockIdx.x * 256 + threadIdx.x;  // B*DI*DST = 16384
  int dn = idx & (DId * DSTd - 1);
  int b  = idx >> 13;
  float H = 0.f;
  for (int c = 0; c < NCh; c++) {
    size_t o = ((size_t)(b * NCh + c)) * (DId * DSTd) + dn;
    Hinit[o] = H;
    H = fmaf(Pst[o], H, hloc[o]);
  }
}

// pass3: rerun chunk scan with correct h0; y = C.h; uc <- (y+u*D)*silu(z)
__global__ __launch_bounds__(256) void scan3_kernel(
    const float* __restrict__ dtf, float* __restrict__ uc,
    const float* __restrict__ xdbl, const float* __restrict__ xz,
    const float* __restrict__ A_log, const float* __restrict__ Dv,
    const float* __restrict__ Hinit)
{
  __shared__ float BCsh[CS][32];
  int tid = threadIdx.x;
  int bx = blockIdx.x;
  int dh = bx & 1, c = (bx >> 1) & (NCh - 1), b = bx >> 8;
  int d = dh * 256 + tid;
  size_t base = (size_t)b * Lseq + (size_t)c * CS;
  for (int i = tid; i < CS * 32; i += 256) {
    int t = i >> 5, j = i & 31;
    BCsh[t][j] = xdbl[(base + t) * 48 + DTRd + j];
  }
  float A[16];
  #pragma unroll
  for (int n = 0; n < 16; n++) A[n] = -__expf(A_log[d * 16 + n]);
  __syncthreads();
  size_t so = (((size_t)(b * NCh + c) * DId) + d) * 16;
  float h[16];
  #pragma unroll
  for (int n = 0; n < 16; n++) h[n] = Hinit[so + n];
  float Dd = Dv[d];
  #pragma unroll 2
  for (int t = 0; t < CS; t++) {
    size_t row = base + t;
    float dt = dtf[row * DId + d];
    float u  = uc [row * DId + d];
    float z  = xz [row * (2*DId) + DId + d];
    float du = dt * u;
    float y = 0.f;
    #pragma unroll
    for (int n = 0; n < 16; n++) {
      float dA = __expf(dt * A[n]);
      h[n] = fmaf(dA, h[n], du * BCsh[t][n]);
      y = fmaf(h[n], BCsh[t][16 + n], y);
    }
    uc[row * DId + d] = (y + u * Dd) * siluf(z);
  }
}

extern "C" void kernel_launch(void* const* d_in, const int* in_sizes, int n_in,
                              void* d_out, int out_size, void* d_ws, size_t ws_size,
                              hipStream_t stream)
{
  const float* x          = (const float*)d_in[0];
  const float* midW_in    = (const float*)d_in[1];
  const float* midW_convw = (const float*)d_in[2];
  const float* midW_convb = (const float*)d_in[3];
  const float* midW_x     = (const float*)d_in[4];
  const float* midW_dtw   = (const float*)d_in[5];
  const float* midW_dtb   = (const float*)d_in[6];
  const float* midA_log   = (const float*)d_in[7];
  const float* midD       = (const float*)d_in[8];
  const float* midW_out   = (const float*)d_in[9];
  const float* midLNw     = (const float*)d_in[10];
  const float* midLNb     = (const float*)d_in[11];
  const float* finW_in    = (const float*)d_in[12];
  const float* finW_convw = (const float*)d_in[13];
  const float* finW_convb = (const float*)d_in[14];
  const float* finW_x     = (const float*)d_in[15];
  const float* finW_dtw   = (const float*)d_in[16];
  const float* finW_dtb   = (const float*)d_in[17];
  const float* finA_log   = (const float*)d_in[18];
  const float* finD       = (const float*)d_in[19];
  const float* finW_out   = (const float*)d_in[20];
  const float* finLNw     = (const float*)d_in[21];
  const float* finLNb     = (const float*)d_in[22];

  // workspace layout (floats), total ~102 MB.
  // hloc aliases hbuf (dead during scans), Pst aliases hn (dead after gemm1).
  float* ws    = (float*)d_ws;
  float* res   = ws;                    // 2,097,152
  float* hn    = res   + 2097152;       // 2,097,152
  float* hbuf  = hn    + 2097152;       // 2,097,152
  float* xz    = hbuf  + 2097152;       // 8,388,608
  float* uc    = xz    + 8388608;       // 4,194,304
  float* xdbl  = uc    + 4194304;       // 393,216
  float* dtf   = xdbl  + 393216;        // 4,194,304
  float* Hinit = dtf   + 4194304;       // 2,097,152
  float* hloc  = hbuf;                  // alias: B*NCh*DI*DST = 2,097,152
  float* Pst   = hn;                    // alias: 2,097,152

  for (int blk = 0; blk < 3; blk++) {
    const float *Win, *convw, *convb, *Wx, *dtw, *dtb, *Alog, *Dv, *Wout, *lnw, *lnb;
    int Nout;
    if (blk < 2) {
      Win   = midW_in    + (size_t)blk * 2*DId*DMdim;
      convw = midW_convw + (size_t)blk * DId*3;
      convb = midW_convb + (size_t)blk * DId;
      Wx    = midW_x     + (size_t)blk * 48*DId;
      dtw   = midW_dtw   + (size_t)blk * DId*DTRd;
      dtb   = midW_dtb   + (size_t)blk * DId;
      Alog  = midA_log   + (size_t)blk * DId*DSTd;
      Dv    = midD       + (size_t)blk * DId;
      Wout  = midW_out   + (size_t)blk * DMdim*DId;
      lnw   = midLNw     + (size_t)blk * DMdim;
      lnb   = midLNb     + (size_t)blk * DMdim;
      Nout  = DMdim;
    } else {
      Win = finW_in; convw = finW_convw; convb = finW_convb; Wx = finW_x;
      dtw = finW_dtw; dtb = finW_dtb; Alog = finA_log; Dv = finD;
      Wout = finW_out; lnw = finLNw; lnb = finLNb;
      Nout = DOUTd;
    }
    const float* addsrc = (blk == 0) ? x : hbuf;
    resid_ln_kernel<<<NROWS, 256, 0, stream>>>(addsrc, res, hn, lnw, lnb, blk == 0 ? 1 : 0);

    dim3 g1(NROWS/64, (2*DId)/64);
    gemm_nt_kernel<<<g1, 256, 0, stream>>>(hn, Win, xz, NROWS, 2*DId, DMdim);

    conv_silu_kernel<<<(NROWS*DId)/256, 256, 0, stream>>>(xz, convw, convb, uc);

    dim3 g2(NROWS/64, 1);
    gemm_nt_kernel<<<g2, 256, 0, stream>>>(uc, Wx, xdbl, NROWS, 48, DId);

    dt_kernel<<<(NROWS*DId)/256, 256, 0, stream>>>(xdbl, dtw, dtb, dtf);

    scan1_kernel<<<Bsz*NCh*2, 256, 0, stream>>>(dtf, uc, xdbl, Alog, hloc, Pst);
    scan2_kernel<<<64, 256, 0, stream>>>(hloc, Pst, Hinit);
    scan3_kernel<<<Bsz*NCh*2, 256, 0, stream>>>(dtf, uc, xdbl, xz, Alog, Dv, Hinit);

    float* Cout = (blk == 2) ? (float*)d_out : hbuf;
    dim3 g3(NROWS/64, Nout/64);
    gemm_nt_kernel<<<g3, 256, 0, stream>>>(uc, Wout, Cout, NROWS, Nout, DId);
  }
}

// Round 3
// 593.891 us; speedup vs baseline: 1.7783x; 1.3790x over previous
//
#include <hip/hip_runtime.h>
#include <math.h>

#define Bsz   2
#define Lseq  4096
#define DMdim 256
#define DOUTd 128
#define DSTd  16
#define DId   512
#define DTRd  16
#define CS    32
#define NCh   128
#define NROWS (Bsz*Lseq)   // 8192

typedef short bf16x8 __attribute__((ext_vector_type(8)));
typedef float f32x4  __attribute__((ext_vector_type(4)));

__device__ __forceinline__ float siluf(float x) { return x / (1.f + __expf(-x)); }
__device__ __forceinline__ float softplusf(float x) {
  return fmaxf(x, 0.f) + log1pf(__expf(-fabsf(x)));
}
__device__ __forceinline__ unsigned short f2bf(float f) {
  union { float f; unsigned int u; } v; v.f = f;
  unsigned int r = v.u + 0x7fffu + ((v.u >> 16) & 1u);   // RNE
  return (unsigned short)(r >> 16);
}

// one-shot weight conversion: 6 segments fp32 -> bf16
__global__ __launch_bounds__(256) void convert6_kernel(
    const float* __restrict__ s0, const float* __restrict__ s1, const float* __restrict__ s2,
    const float* __restrict__ s3, const float* __restrict__ s4, const float* __restrict__ s5,
    unsigned short* __restrict__ d0, unsigned short* __restrict__ d1, unsigned short* __restrict__ d2,
    unsigned short* __restrict__ d3, unsigned short* __restrict__ d4, unsigned short* __restrict__ d5,
    int n0, int n1, int n2, int n3, int n4, int n5)
{
  int i = blockIdx.x * 256 + threadIdx.x;
  int c0 = n0, c1 = c0 + n1, c2 = c1 + n2, c3 = c2 + n3, c4 = c3 + n4, c5 = c4 + n5;
  if (i >= c5) return;
  if      (i < c0) d0[i]      = f2bf(s0[i]);
  else if (i < c1) d1[i - c0] = f2bf(s1[i - c0]);
  else if (i < c2) d2[i - c1] = f2bf(s2[i - c1]);
  else if (i < c3) d3[i - c2] = f2bf(s3[i - c2]);
  else if (i < c4) d4[i - c3] = f2bf(s4[i - c3]);
  else             d5[i - c4] = f2bf(s5[i - c4]);
}

// res = (first ? x : res + h); hnb = bf16(LN(res)*w + b)
__global__ __launch_bounds__(256) void resid_ln_kernel(
    const float* __restrict__ addsrc, float* __restrict__ res, unsigned short* __restrict__ hnb,
    const float* __restrict__ w, const float* __restrict__ b, int first)
{
  int row = blockIdx.x;
  int t = threadIdx.x;
  size_t o = (size_t)row * DMdim + t;
  float v = first ? addsrc[o] : (res[o] + addsrc[o]);
  res[o] = v;
  float s1 = v, s2 = v * v;
  #pragma unroll
  for (int m = 32; m >= 1; m >>= 1) {
    s1 += __shfl_xor(s1, m, 64);
    s2 += __shfl_xor(s2, m, 64);
  }
  __shared__ float w1[4], w2[4];
  int wid = t >> 6, ln = t & 63;
  if (ln == 0) { w1[wid] = s1; w2[wid] = s2; }
  __syncthreads();
  float S1 = w1[0] + w1[1] + w1[2] + w1[3];
  float S2 = w2[0] + w2[1] + w2[2] + w2[3];
  float mean = S1 * (1.f / DMdim);
  float var  = S2 * (1.f / DMdim) - mean * mean;
  float r = rsqrtf(var + 1e-5f);
  hnb[o] = f2bf((v - mean) * r * w[t] + b[t]);
}

// bf16 MFMA GEMM, NT: C[m,n] = sum_k A[m,k]*W[n,k]. A:(M,K) bf16, W:(N,K) bf16, C fp32.
// tile 128x64, BK=32, 256 threads = 4 waves in 2x2; wave computes 64x32 (4x2 subtiles).
__global__ __launch_bounds__(256) void gemm_bf_kernel(
    const unsigned short* __restrict__ A, const unsigned short* __restrict__ W,
    float* __restrict__ C, int N, int K)
{
  __shared__ unsigned short Abuf[4][128][8];   // [kchunk][m][8k]
  __shared__ unsigned short Bbuf[4][64][8];    // [kchunk][n][8k]
  int tid = threadIdx.x;
  int bm = blockIdx.x * 128;
  int bn = blockIdx.y * 64;
  int wid = tid >> 6, lane = tid & 63;
  int wm = wid >> 1, wn = wid & 1;
  int l15 = lane & 15, kh = lane >> 4;
  int r4 = tid >> 2;   // 0..63
  int c4 = tid & 3;    // k chunk
  f32x4 acc[4][2];
  #pragma unroll
  for (int i = 0; i < 4; i++)
    #pragma unroll
    for (int j = 0; j < 2; j++)
      #pragma unroll
      for (int r = 0; r < 4; r++) acc[i][j][r] = 0.f;

  for (int k0 = 0; k0 < K; k0 += 32) {
    const unsigned short* ga  = A + (size_t)(bm + r4) * K + k0 + c4 * 8;
    const unsigned short* ga2 = A + (size_t)(bm + 64 + r4) * K + k0 + c4 * 8;
    *(bf16x8*)&Abuf[c4][r4][0]      = *(const bf16x8*)ga;
    *(bf16x8*)&Abuf[c4][64 + r4][0] = *(const bf16x8*)ga2;
    int wr = bn + r4;
    bf16x8 wv;
    #pragma unroll
    for (int e = 0; e < 8; e++) wv[e] = 0;
    if (wr < N) wv = *(const bf16x8*)(W + (size_t)wr * K + k0 + c4 * 8);
    *(bf16x8*)&Bbuf[c4][r4][0] = wv;
    __syncthreads();
    bf16x8 af[4], bfr[2];
    #pragma unroll
    for (int i = 0; i < 4; i++)
      af[i] = *(const bf16x8*)&Abuf[kh][wm * 64 + i * 16 + l15][0];
    #pragma unroll
    for (int j = 0; j < 2; j++)
      bfr[j] = *(const bf16x8*)&Bbuf[kh][wn * 32 + j * 16 + l15][0];
    #pragma unroll
    for (int i = 0; i < 4; i++)
      #pragma unroll
      for (int j = 0; j < 2; j++)
        acc[i][j] = __builtin_amdgcn_mfma_f32_16x16x32_bf16(af[i], bfr[j], acc[i][j], 0, 0, 0);
    __syncthreads();
  }
  // D layout: n = lane&15, m = (lane>>4)*4 + reg
  int mrow0 = bm + wm * 64 + (kh << 2);
  int ncol0 = bn + wn * 32 + l15;
  #pragma unroll
  for (int i = 0; i < 4; i++) {
    #pragma unroll
    for (int j = 0; j < 2; j++) {
      int n = ncol0 + j * 16;
      if (n < N) {
        #pragma unroll
        for (int r = 0; r < 4; r++)
          C[(size_t)(mrow0 + i * 16 + r) * N + n] = acc[i][j][r];
      }
    }
  }
}

// ucb[b,l,d] = bf16(silu(conv(xz_u))) — GEMM operand for W_x
__global__ __launch_bounds__(256) void conv_silu_kernel(
    const float* __restrict__ xz, const float* __restrict__ cw,
    const float* __restrict__ cb, unsigned short* __restrict__ ucb)
{
  int idx = blockIdx.x * 256 + threadIdx.x;
  int d  = idx & (DId - 1);
  int bl = idx >> 9;
  int l  = bl & (Lseq - 1);
  float w0 = cw[d*3+0], w1 = cw[d*3+1], w2 = cw[d*3+2];
  float acc = cb[d];
  acc = fmaf(xz[(size_t)bl * (2*DId) + d], w2, acc);
  if (l >= 1) acc = fmaf(xz[(size_t)(bl-1) * (2*DId) + d], w1, acc);
  if (l >= 2) acc = fmaf(xz[(size_t)(bl-2) * (2*DId) + d], w0, acc);
  ucb[idx] = f2bf(siluf(acc));
}

// pass1: one thread per (b,chunk,d); recompute u and dt in fp32; h[16] regs, h0=0.
__global__ __launch_bounds__(256) void scan1_kernel(
    const float* __restrict__ xz, const float* __restrict__ xdbl,
    const float* __restrict__ cw, const float* __restrict__ cb,
    const float* __restrict__ dtw, const float* __restrict__ dtb,
    const float* __restrict__ A_log,
    float* __restrict__ hloc, float* __restrict__ Pst)
{
  __shared__ float Xsh[CS][32];   // cols 0..15 dt-raw, 16..31 B
  int tid = threadIdx.x;
  int bx = blockIdx.x;
  int dh = bx & 1, c = (bx >> 1) & (NCh - 1), b = bx >> 8;
  int d = dh * 256 + tid;
  size_t base = (size_t)b * Lseq + (size_t)c * CS;
  for (int i = tid; i < CS * 32; i += 256) {
    int t = i >> 5, col = i & 31;
    Xsh[t][col] = xdbl[(base + t) * 48 + col];
  }
  float A[16], wdt[16];
  #pragma unroll
  for (int n = 0; n < 16; n++) A[n] = -__expf(A_log[d * 16 + n]);
  #pragma unroll
  for (int n = 0; n < 16; n++) wdt[n] = dtw[d * 16 + n];
  float cw0 = cw[d*3+0], cw1 = cw[d*3+1], cw2 = cw[d*3+2], cbd = cb[d], dtbd = dtb[d];
  __syncthreads();
  float h[16];
  #pragma unroll
  for (int n = 0; n < 16; n++) h[n] = 0.f;
  float sdt = 0.f;
  int l0 = c * CS;
  for (int t = 0; t < CS; t++) {
    size_t row = base + t;
    int l = l0 + t;
    // u = silu(conv)
    float a = cbd;
    a = fmaf(xz[row * (2*DId) + d], cw2, a);
    if (l >= 1) a = fmaf(xz[(row-1) * (2*DId) + d], cw1, a);
    if (l >= 2) a = fmaf(xz[(row-2) * (2*DId) + d], cw0, a);
    float u = siluf(a);
    // dt = softplus(dtraw . wdt + dtb)
    float dr = dtbd;
    #pragma unroll
    for (int r = 0; r < 16; r++) dr = fmaf(Xsh[t][r], wdt[r], dr);
    float dt = softplusf(dr);
    float du = dt * u;
    sdt += dt;
    #pragma unroll
    for (int n = 0; n < 16; n++) {
      float dA = __expf(dt * A[n]);
      h[n] = fmaf(dA, h[n], du * Xsh[t][16 + n]);
    }
  }
  size_t so = (((size_t)(b * NCh + c) * DId) + d) * 16;
  #pragma unroll
  for (int n = 0; n < 16; n++) {
    hloc[so + n] = h[n];
    Pst [so + n] = __expf(sdt * A[n]);
  }
}

// pass2: sequential scan over chunks; store incoming state per chunk
__global__ __launch_bounds__(256) void scan2_kernel(
    const float* __restrict__ hloc, const float* __restrict__ Pst,
    float* __restrict__ Hinit)
{
  int idx = blockIdx.x * 256 + threadIdx.x;  // B*DI*DST = 16384
  int dn = idx & (DId * DSTd - 1);
  int b  = idx >> 13;
  float H = 0.f;
  for (int c = 0; c < NCh; c++) {
    size_t o = ((size_t)(b * NCh + c)) * (DId * DSTd) + dn;
    Hinit[o] = H;
    H = fmaf(Pst[o], H, hloc[o]);
  }
}

// pass3: rerun with correct h0; y = C.h; yb = bf16((y+u*D)*silu(z))
__global__ __launch_bounds__(256) void scan3_kernel(
    const float* __restrict__ xz, const float* __restrict__ xdbl,
    const float* __restrict__ cw, const float* __restrict__ cb,
    const float* __restrict__ dtw, const float* __restrict__ dtb,
    const float* __restrict__ A_log, const float* __restrict__ Dv,
    const float* __restrict__ Hinit, unsigned short* __restrict__ yb)
{
  __shared__ float Xsh[CS][48];   // 0..15 dt-raw, 16..31 B, 32..47 C
  int tid = threadIdx.x;
  int bx = blockIdx.x;
  int dh = bx & 1, c = (bx >> 1) & (NCh - 1), b = bx >> 8;
  int d = dh * 256 + tid;
  size_t base = (size_t)b * Lseq + (size_t)c * CS;
  for (int i = tid; i < CS * 48; i += 256) {
    int t = i / 48, col = i - t * 48;
    Xsh[t][col] = xdbl[(base + t) * 48 + col];
  }
  float A[16], wdt[16];
  #pragma unroll
  for (int n = 0; n < 16; n++) A[n] = -__expf(A_log[d * 16 + n]);
  #pragma unroll
  for (int n = 0; n < 16; n++) wdt[n] = dtw[d * 16 + n];
  float cw0 = cw[d*3+0], cw1 = cw[d*3+1], cw2 = cw[d*3+2], cbd = cb[d], dtbd = dtb[d];
  float Dd = Dv[d];
  __syncthreads();
  size_t so = (((size_t)(b * NCh + c) * DId) + d) * 16;
  float h[16];
  #pragma unroll
  for (int n = 0; n < 16; n++) h[n] = Hinit[so + n];
  int l0 = c * CS;
  for (int t = 0; t < CS; t++) {
    size_t row = base + t;
    int l = l0 + t;
    float a = cbd;
    a = fmaf(xz[row * (2*DId) + d], cw2, a);
    if (l >= 1) a = fmaf(xz[(row-1) * (2*DId) + d], cw1, a);
    if (l >= 2) a = fmaf(xz[(row-2) * (2*DId) + d], cw0, a);
    float u = siluf(a);
    float dr = dtbd;
    #pragma unroll
    for (int r = 0; r < 16; r++) dr = fmaf(Xsh[t][r], wdt[r], dr);
    float dt = softplusf(dr);
    float du = dt * u;
    float y = 0.f;
    #pragma unroll
    for (int n = 0; n < 16; n++) {
      float dA = __expf(dt * A[n]);
      h[n] = fmaf(dA, h[n], du * Xsh[t][16 + n]);
      y = fmaf(h[n], Xsh[t][32 + n], y);
    }
    float z = xz[row * (2*DId) + DId + d];
    yb[row * DId + d] = f2bf((y + u * Dd) * siluf(z));
  }
}

extern "C" void kernel_launch(void* const* d_in, const int* in_sizes, int n_in,
                              void* d_out, int out_size, void* d_ws, size_t ws_size,
                              hipStream_t stream)
{
  const float* x          = (const float*)d_in[0];
  const float* midW_in    = (const float*)d_in[1];
  const float* midW_convw = (const float*)d_in[2];
  const float* midW_convb = (const float*)d_in[3];
  const float* midW_x     = (const float*)d_in[4];
  const float* midW_dtw   = (const float*)d_in[5];
  const float* midW_dtb   = (const float*)d_in[6];
  const float* midA_log   = (const float*)d_in[7];
  const float* midD       = (const float*)d_in[8];
  const float* midW_out   = (const float*)d_in[9];
  const float* midLNw     = (const float*)d_in[10];
  const float* midLNb     = (const float*)d_in[11];
  const float* finW_in    = (const float*)d_in[12];
  const float* finW_convw = (const float*)d_in[13];
  const float* finW_convb = (const float*)d_in[14];
  const float* finW_x     = (const float*)d_in[15];
  const float* finW_dtw   = (const float*)d_in[16];
  const float* finW_dtb   = (const float*)d_in[17];
  const float* finA_log   = (const float*)d_in[18];
  const float* finD       = (const float*)d_in[19];
  const float* finW_out   = (const float*)d_in[20];
  const float* finLNw     = (const float*)d_in[21];
  const float* finLNb     = (const float*)d_in[22];

  // workspace layout: fp32 region then bf16 region (~100 MB total)
  float* ws    = (float*)d_ws;
  float* res   = ws;                    // 2,097,152
  float* xz    = res   + 2097152;       // 8,388,608
  float* xdbl  = xz    + 8388608;       // 393,216
  float* hloc  = xdbl  + 393216;        // 2,097,152
  float* Pst   = hloc  + 2097152;       // 2,097,152
  float* Hinit = Pst   + 2097152;       // 2,097,152
  float* hbuf  = Hinit + 2097152;       // 2,097,152
  unsigned short* us = (unsigned short*)(hbuf + 2097152);
  unsigned short* hnb   = us;                 // 2,097,152
  unsigned short* ucb   = hnb  + 2097152;     // 4,194,304
  unsigned short* yb    = ucb  + 4194304;     // 4,194,304
  unsigned short* wWin  = yb   + 4194304;     // 524,288 (2 layers)
  unsigned short* wWx   = wWin + 524288;      // 49,152
  unsigned short* wWout = wWx  + 49152;       // 262,144
  unsigned short* wfWin = wWout+ 262144;      // 262,144
  unsigned short* wfWx  = wfWin+ 262144;      // 24,576
  unsigned short* wfWout= wfWx + 24576;       // 65,536

  {
    int n0 = 524288, n1 = 49152, n2 = 262144, n3 = 262144, n4 = 24576, n5 = 65536;
    int tot = n0 + n1 + n2 + n3 + n4 + n5;
    convert6_kernel<<<(tot + 255) / 256, 256, 0, stream>>>(
        midW_in, midW_x, midW_out, finW_in, finW_x, finW_out,
        wWin, wWx, wWout, wfWin, wfWx, wfWout,
        n0, n1, n2, n3, n4, n5);
  }

  for (int blk = 0; blk < 3; blk++) {
    const unsigned short *Winb, *Wxb, *Woutb;
    const float *convw, *convb, *dtw, *dtb, *Alog, *Dv, *lnw, *lnb;
    int Nout;
    if (blk < 2) {
      Winb  = wWin  + (size_t)blk * 2*DId*DMdim;
      Wxb   = wWx   + (size_t)blk * 48*DId;
      Woutb = wWout + (size_t)blk * DMdim*DId;
      convw = midW_convw + (size_t)blk * DId*3;
      convb = midW_convb + (size_t)blk * DId;
      dtw   = midW_dtw   + (size_t)blk * DId*DTRd;
      dtb   = midW_dtb   + (size_t)blk * DId;
      Alog  = midA_log   + (size_t)blk * DId*DSTd;
      Dv    = midD       + (size_t)blk * DId;
      lnw   = midLNw     + (size_t)blk * DMdim;
      lnb   = midLNb     + (size_t)blk * DMdim;
      Nout  = DMdim;
    } else {
      Winb = wfWin; Wxb = wfWx; Woutb = wfWout;
      convw = finW_convw; convb = finW_convb;
      dtw = finW_dtw; dtb = finW_dtb; Alog = finA_log; Dv = finD;
      lnw = finLNw; lnb = finLNb;
      Nout = DOUTd;
    }
    const float* addsrc = (blk == 0) ? x : hbuf;
    resid_ln_kernel<<<NROWS, 256, 0, stream>>>(addsrc, res, hnb, lnw, lnb, blk == 0 ? 1 : 0);

    dim3 g1(NROWS/128, (2*DId)/64);
    gemm_bf_kernel<<<g1, 256, 0, stream>>>(hnb, Winb, xz, 2*DId, DMdim);

    conv_silu_kernel<<<(NROWS*DId)/256, 256, 0, stream>>>(xz, convw, convb, ucb);

    dim3 g2(NROWS/128, 1);
    gemm_bf_kernel<<<g2, 256, 0, stream>>>(ucb, Wxb, xdbl, 48, DId);

    scan1_kernel<<<Bsz*NCh*2, 256, 0, stream>>>(xz, xdbl, convw, convb, dtw, dtb, Alog, hloc, Pst);
    scan2_kernel<<<64, 256, 0, stream>>>(hloc, Pst, Hinit);
    scan3_kernel<<<Bsz*NCh*2, 256, 0, stream>>>(xz, xdbl, convw, convb, dtw, dtb, Alog, Dv, Hinit, yb);

    float* Cout = (blk == 2) ? (float*)d_out : hbuf;
    dim3 g3(NROWS/128, (Nout + 63)/64);
    gemm_bf_kernel<<<g3, 256, 0, stream>>>(yb, Woutb, Cout, Nout, DId);
  }
}

// Round 4
// 550.261 us; speedup vs baseline: 1.9193x; 1.0793x over previous
//
#include <hip/hip_runtime.h>
#include <math.h>

#define Bsz   2
#define Lseq  4096
#define DMdim 256
#define DOUTd 128
#define DSTd  16
#define DId   512
#define DTRd  16
#define CS    32
#define NCh   128
#define NROWS (Bsz*Lseq)   // 8192

typedef short bf16x8 __attribute__((ext_vector_type(8)));
typedef float f32x4  __attribute__((ext_vector_type(4)));

#if __has_builtin(__builtin_amdgcn_exp2f)
#define EXP2F(x) __builtin_amdgcn_exp2f(x)
#else
#define EXP2F(x) __expf((x) * 0.69314718056f)
#endif
#define LOG2E 1.44269504f

__device__ __forceinline__ float siluf(float x) { return x / (1.f + __expf(-x)); }
__device__ __forceinline__ float softplusf(float x) {
  return fmaxf(x, 0.f) + log1pf(__expf(-fabsf(x)));
}
__device__ __forceinline__ unsigned short f2bf(float f) {
  union { float f; unsigned int u; } v; v.f = f;
  unsigned int r = v.u + 0x7fffu + ((v.u >> 16) & 1u);   // RNE
  return (unsigned short)(r >> 16);
}
__device__ __forceinline__ float bf2f(unsigned short h) {
  union { unsigned int u; float f; } v; v.u = ((unsigned int)h) << 16;
  return v.f;
}

// one-shot weight conversion: 6 segments fp32 -> bf16
__global__ __launch_bounds__(256) void convert6_kernel(
    const float* __restrict__ s0, const float* __restrict__ s1, const float* __restrict__ s2,
    const float* __restrict__ s3, const float* __restrict__ s4, const float* __restrict__ s5,
    unsigned short* __restrict__ d0, unsigned short* __restrict__ d1, unsigned short* __restrict__ d2,
    unsigned short* __restrict__ d3, unsigned short* __restrict__ d4, unsigned short* __restrict__ d5,
    int n0, int n1, int n2, int n3, int n4, int n5)
{
  int i = blockIdx.x * 256 + threadIdx.x;
  int c0 = n0, c1 = c0 + n1, c2 = c1 + n2, c3 = c2 + n3, c4 = c3 + n4, c5 = c4 + n5;
  if (i >= c5) return;
  if      (i < c0) d0[i]      = f2bf(s0[i]);
  else if (i < c1) d1[i - c0] = f2bf(s1[i - c0]);
  else if (i < c2) d2[i - c1] = f2bf(s2[i - c1]);
  else if (i < c3) d3[i - c2] = f2bf(s3[i - c2]);
  else if (i < c4) d4[i - c3] = f2bf(s4[i - c3]);
  else             d5[i - c4] = f2bf(s5[i - c4]);
}

// res = (first ? x : res + h); hnb = bf16(LN(res)*w + b)
__global__ __launch_bounds__(256) void resid_ln_kernel(
    const float* __restrict__ addsrc, float* __restrict__ res, unsigned short* __restrict__ hnb,
    const float* __restrict__ w, const float* __restrict__ b, int first)
{
  int row = blockIdx.x;
  int t = threadIdx.x;
  size_t o = (size_t)row * DMdim + t;
  float v = first ? addsrc[o] : (res[o] + addsrc[o]);
  res[o] = v;
  float s1 = v, s2 = v * v;
  #pragma unroll
  for (int m = 32; m >= 1; m >>= 1) {
    s1 += __shfl_xor(s1, m, 64);
    s2 += __shfl_xor(s2, m, 64);
  }
  __shared__ float w1[4], w2[4];
  int wid = t >> 6, ln = t & 63;
  if (ln == 0) { w1[wid] = s1; w2[wid] = s2; }
  __syncthreads();
  float S1 = w1[0] + w1[1] + w1[2] + w1[3];
  float S2 = w2[0] + w2[1] + w2[2] + w2[3];
  float mean = S1 * (1.f / DMdim);
  float var  = S2 * (1.f / DMdim) - mean * mean;
  float r = rsqrtf(var + 1e-5f);
  hnb[o] = f2bf((v - mean) * r * w[t] + b[t]);
}

// bf16 MFMA GEMM, NT: C[m,n] = sum_k A[m,k]*W[n,k].
// Output split: cols [0,split) -> C0 (row stride min(split,N)), cols [split,N) -> C1 (row stride N-split).
__global__ __launch_bounds__(256) void gemm_bf_kernel(
    const unsigned short* __restrict__ A, const unsigned short* __restrict__ W,
    float* __restrict__ C0, float* __restrict__ C1, int split, int N, int K)
{
  __shared__ unsigned short Abuf[4][128][8];   // [kchunk][m][8k]
  __shared__ unsigned short Bbuf[4][64][8];    // [kchunk][n][8k]
  int tid = threadIdx.x;
  int bm = blockIdx.x * 128;
  int bn = blockIdx.y * 64;
  int wid = tid >> 6, lane = tid & 63;
  int wm = wid >> 1, wn = wid & 1;
  int l15 = lane & 15, kh = lane >> 4;
  int r4 = tid >> 2;   // 0..63
  int c4 = tid & 3;    // k chunk
  f32x4 acc[4][2];
  #pragma unroll
  for (int i = 0; i < 4; i++)
    #pragma unroll
    for (int j = 0; j < 2; j++)
      #pragma unroll
      for (int r = 0; r < 4; r++) acc[i][j][r] = 0.f;

  for (int k0 = 0; k0 < K; k0 += 32) {
    const unsigned short* ga  = A + (size_t)(bm + r4) * K + k0 + c4 * 8;
    const unsigned short* ga2 = A + (size_t)(bm + 64 + r4) * K + k0 + c4 * 8;
    *(bf16x8*)&Abuf[c4][r4][0]      = *(const bf16x8*)ga;
    *(bf16x8*)&Abuf[c4][64 + r4][0] = *(const bf16x8*)ga2;
    int wr = bn + r4;
    bf16x8 wv;
    #pragma unroll
    for (int e = 0; e < 8; e++) wv[e] = 0;
    if (wr < N) wv = *(const bf16x8*)(W + (size_t)wr * K + k0 + c4 * 8);
    *(bf16x8*)&Bbuf[c4][r4][0] = wv;
    __syncthreads();
    bf16x8 af[4], bfr[2];
    #pragma unroll
    for (int i = 0; i < 4; i++)
      af[i] = *(const bf16x8*)&Abuf[kh][wm * 64 + i * 16 + l15][0];
    #pragma unroll
    for (int j = 0; j < 2; j++)
      bfr[j] = *(const bf16x8*)&Bbuf[kh][wn * 32 + j * 16 + l15][0];
    #pragma unroll
    for (int i = 0; i < 4; i++)
      #pragma unroll
      for (int j = 0; j < 2; j++)
        acc[i][j] = __builtin_amdgcn_mfma_f32_16x16x32_bf16(af[i], bfr[j], acc[i][j], 0, 0, 0);
    __syncthreads();
  }
  // D layout: n = lane&15, m = (lane>>4)*4 + reg
  int s0 = (split < N) ? split : N;
  int s1 = N - split;
  int mrow0 = bm + wm * 64 + (kh << 2);
  int ncol0 = bn + wn * 32 + l15;
  #pragma unroll
  for (int i = 0; i < 4; i++) {
    #pragma unroll
    for (int j = 0; j < 2; j++) {
      int n = ncol0 + j * 16;
      if (n < N) {
        #pragma unroll
        for (int r = 0; r < 4; r++) {
          int m = mrow0 + i * 16 + r;
          if (n < split) C0[(size_t)m * s0 + n] = acc[i][j][r];
          else           C1[(size_t)m * s1 + (n - split)] = acc[i][j][r];
        }
      }
    }
  }
}

// ucb[bl,d] = bf16(silu(conv(ub)))
__global__ __launch_bounds__(256) void conv_silu_kernel(
    const float* __restrict__ ub, const float* __restrict__ cw,
    const float* __restrict__ cb, unsigned short* __restrict__ ucb)
{
  int idx = blockIdx.x * 256 + threadIdx.x;
  int d  = idx & (DId - 1);
  int bl = idx >> 9;
  int l  = bl & (Lseq - 1);
  float w0 = cw[d*3+0], w1 = cw[d*3+1], w2 = cw[d*3+2];
  float acc = cb[d];
  acc = fmaf(ub[(size_t)bl * DId + d], w2, acc);
  if (l >= 1) acc = fmaf(ub[(size_t)(bl-1) * DId + d], w1, acc);
  if (l >= 2) acc = fmaf(ub[(size_t)(bl-2) * DId + d], w0, acc);
  ucb[idx] = f2bf(siluf(acc));
}

// dtf[bl,d] = softplus(xdbl[bl,0:16] . dtw[d,:] + dtb[d])   (fp32)
__global__ __launch_bounds__(256) void dt_kernel(
    const float* __restrict__ xdbl, const float* __restrict__ dtw,
    const float* __restrict__ dtb, float* __restrict__ dtf)
{
  int idx = blockIdx.x * 256 + threadIdx.x;
  int d  = idx & (DId - 1);
  int bl = idx >> 9;
  const float* dp = xdbl + (size_t)bl * 48;   // wave-uniform address
  float a = dtb[d];
  #pragma unroll
  for (int r = 0; r < 16; r++) a = fmaf(dp[r], dtw[d*16 + r], a);
  dtf[idx] = softplusf(a);
}

// pass1: thread per (b,chunk,d); h[16] regs, h0=0; slim loop (dt/u precomputed).
__global__ __launch_bounds__(256) void scan1_kernel(
    const float* __restrict__ dtf, const unsigned short* __restrict__ ucb,
    const float* __restrict__ xdbl, const float* __restrict__ A_log,
    float* __restrict__ hloc, float* __restrict__ Pst)
{
  int tid = threadIdx.x;
  int bx = blockIdx.x;
  int dh = bx & 1, c = (bx >> 1) & (NCh - 1), b = bx >> 8;
  int d = dh * 256 + tid;
  size_t base = (size_t)b * Lseq + (size_t)c * CS;
  float A2[16];
  #pragma unroll
  for (int q = 0; q < 4; q++) {
    float4 av = *(const float4*)(A_log + d * 16 + q * 4);
    A2[q*4+0] = -__expf(av.x) * LOG2E;
    A2[q*4+1] = -__expf(av.y) * LOG2E;
    A2[q*4+2] = -__expf(av.z) * LOG2E;
    A2[q*4+3] = -__expf(av.w) * LOG2E;
  }
  const float* Bc = xdbl + base * 48 + DTRd;   // wave-uniform
  float h[16];
  #pragma unroll
  for (int n = 0; n < 16; n++) h[n] = 0.f;
  float sdt = 0.f;
  #pragma unroll 2
  for (int t = 0; t < CS; t++) {
    size_t row = base + t;
    float dt = dtf[row * DId + d];
    float u  = bf2f(ucb[row * DId + d]);
    float du = dt * u;
    sdt += dt;
    #pragma unroll
    for (int q = 0; q < 4; q++) {
      float4 Bv = *(const float4*)(Bc + t * 48 + q * 4);   // uniform -> s_load
      h[q*4+0] = fmaf(EXP2F(dt * A2[q*4+0]), h[q*4+0], du * Bv.x);
      h[q*4+1] = fmaf(EXP2F(dt * A2[q*4+1]), h[q*4+1], du * Bv.y);
      h[q*4+2] = fmaf(EXP2F(dt * A2[q*4+2]), h[q*4+2], du * Bv.z);
      h[q*4+3] = fmaf(EXP2F(dt * A2[q*4+3]), h[q*4+3], du * Bv.w);
    }
  }
  size_t so = (((size_t)(b * NCh + c) * DId) + d) * 16;
  #pragma unroll
  for (int q = 0; q < 4; q++) {
    float4 hv, pv;
    hv.x = h[q*4+0]; hv.y = h[q*4+1]; hv.z = h[q*4+2]; hv.w = h[q*4+3];
    pv.x = EXP2F(sdt * A2[q*4+0]);
    pv.y = EXP2F(sdt * A2[q*4+1]);
    pv.z = EXP2F(sdt * A2[q*4+2]);
    pv.w = EXP2F(sdt * A2[q*4+3]);
    *(float4*)(hloc + so + q * 4) = hv;
    *(float4*)(Pst  + so + q * 4) = pv;
  }
}

// pass2: sequential scan over chunks; store incoming state per chunk
__global__ __launch_bounds__(256) void scan2_kernel(
    const float* __restrict__ hloc, const float* __restrict__ Pst,
    float* __restrict__ Hinit)
{
  int idx = blockIdx.x * 256 + threadIdx.x;  // B*DI*DST = 16384
  int dn = idx & (DId * DSTd - 1);
  int b  = idx >> 13;
  float H = 0.f;
  for (int c = 0; c < NCh; c++) {
    size_t o = ((size_t)(b * NCh + c)) * (DId * DSTd) + dn;
    Hinit[o] = H;
    H = fmaf(Pst[o], H, hloc[o]);
  }
}

// pass3: rerun with correct h0; y = C.h; yb = bf16((y+u*D)*silu(z))
__global__ __launch_bounds__(256) void scan3_kernel(
    const float* __restrict__ dtf, const unsigned short* __restrict__ ucb,
    const float* __restrict__ xdbl, const float* __restrict__ zb,
    const float* __restrict__ A_log, const float* __restrict__ Dv,
    const float* __restrict__ Hinit, unsigned short* __restrict__ yb)
{
  int tid = threadIdx.x;
  int bx = blockIdx.x;
  int dh = bx & 1, c = (bx >> 1) & (NCh - 1), b = bx >> 8;
  int d = dh * 256 + tid;
  size_t base = (size_t)b * Lseq + (size_t)c * CS;
  float A2[16];
  #pragma unroll
  for (int q = 0; q < 4; q++) {
    float4 av = *(const float4*)(A_log + d * 16 + q * 4);
    A2[q*4+0] = -__expf(av.x) * LOG2E;
    A2[q*4+1] = -__expf(av.y) * LOG2E;
    A2[q*4+2] = -__expf(av.z) * LOG2E;
    A2[q*4+3] = -__expf(av.w) * LOG2E;
  }
  const float* Bc = xdbl + base * 48 + DTRd;
  const float* Cc = Bc + DSTd;
  size_t so = (((size_t)(b * NCh + c) * DId) + d) * 16;
  float h[16];
  #pragma unroll
  for (int q = 0; q < 4; q++) {
    float4 hv = *(const float4*)(Hinit + so + q * 4);
    h[q*4+0] = hv.x; h[q*4+1] = hv.y; h[q*4+2] = hv.z; h[q*4+3] = hv.w;
  }
  float Dd = Dv[d];
  #pragma unroll 2
  for (int t = 0; t < CS; t++) {
    size_t row = base + t;
    float dt = dtf[row * DId + d];
    float u  = bf2f(ucb[row * DId + d]);
    float du = dt * u;
    float y = 0.f;
    #pragma unroll
    for (int q = 0; q < 4; q++) {
      float4 Bv = *(const float4*)(Bc + t * 48 + q * 4);   // uniform -> s_load
      float4 Cv = *(const float4*)(Cc + t * 48 + q * 4);
      h[q*4+0] = fmaf(EXP2F(dt * A2[q*4+0]), h[q*4+0], du * Bv.x);
      h[q*4+1] = fmaf(EXP2F(dt * A2[q*4+1]), h[q*4+1], du * Bv.y);
      h[q*4+2] = fmaf(EXP2F(dt * A2[q*4+2]), h[q*4+2], du * Bv.z);
      h[q*4+3] = fmaf(EXP2F(dt * A2[q*4+3]), h[q*4+3], du * Bv.w);
      y = fmaf(h[q*4+0], Cv.x, y);
      y = fmaf(h[q*4+1], Cv.y, y);
      y = fmaf(h[q*4+2], Cv.z, y);
      y = fmaf(h[q*4+3], Cv.w, y);
    }
    float z = zb[row * DId + d];
    yb[row * DId + d] = f2bf((y + u * Dd) * siluf(z));
  }
}

extern "C" void kernel_launch(void* const* d_in, const int* in_sizes, int n_in,
                              void* d_out, int out_size, void* d_ws, size_t ws_size,
                              hipStream_t stream)
{
  const float* x          = (const float*)d_in[0];
  const float* midW_in    = (const float*)d_in[1];
  const float* midW_convw = (const float*)d_in[2];
  const float* midW_convb = (const float*)d_in[3];
  const float* midW_x     = (const float*)d_in[4];
  const float* midW_dtw   = (const float*)d_in[5];
  const float* midW_dtb   = (const float*)d_in[6];
  const float* midA_log   = (const float*)d_in[7];
  const float* midD       = (const float*)d_in[8];
  const float* midW_out   = (const float*)d_in[9];
  const float* midLNw     = (const float*)d_in[10];
  const float* midLNb     = (const float*)d_in[11];
  const float* finW_in    = (const float*)d_in[12];
  const float* finW_convw = (const float*)d_in[13];
  const float* finW_convb = (const float*)d_in[14];
  const float* finW_x     = (const float*)d_in[15];
  const float* finW_dtw   = (const float*)d_in[16];
  const float* finW_dtb   = (const float*)d_in[17];
  const float* finA_log   = (const float*)d_in[18];
  const float* finD       = (const float*)d_in[19];
  const float* finW_out   = (const float*)d_in[20];
  const float* finLNw     = (const float*)d_in[21];
  const float* finLNb     = (const float*)d_in[22];

  // workspace layout (floats ~77 MB + bf16 ~23 MB = ~100 MB)
  float* ws    = (float*)d_ws;
  float* res   = ws;                    // 2,097,152
  float* zb    = res   + 2097152;       // 4,194,304 (z half of W_in output)
  float* xdbl  = zb    + 4194304;       // 393,216
  float* hloc  = xdbl  + 393216;        // 2,097,152
  float* Pst   = hloc  + 2097152;       // 2,097,152
  float* Hinit = Pst   + 2097152;       // 2,097,152
  float* hbuf  = Hinit + 2097152;       // 2,097,152
  float* ub    = hbuf  + 2097152;       // 4,194,304 (u half; dead after conv)
  float* dtf   = ub;                    // alias: dtf written after conv consumes ub
  unsigned short* us = (unsigned short*)(ub + 4194304);
  unsigned short* hnb   = us;                 // 2,097,152
  unsigned short* ucb   = hnb  + 2097152;     // 4,194,304
  unsigned short* yb    = ucb  + 4194304;     // 4,194,304
  unsigned short* wWin  = yb   + 4194304;     // 524,288 (2 layers)
  unsigned short* wWx   = wWin + 524288;      // 49,152
  unsigned short* wWout = wWx  + 49152;       // 262,144
  unsigned short* wfWin = wWout+ 262144;      // 262,144
  unsigned short* wfWx  = wfWin+ 262144;      // 24,576
  unsigned short* wfWout= wfWx + 24576;       // 65,536

  {
    int n0 = 524288, n1 = 49152, n2 = 262144, n3 = 262144, n4 = 24576, n5 = 65536;
    int tot = n0 + n1 + n2 + n3 + n4 + n5;
    convert6_kernel<<<(tot + 255) / 256, 256, 0, stream>>>(
        midW_in, midW_x, midW_out, finW_in, finW_x, finW_out,
        wWin, wWx, wWout, wfWin, wfWx, wfWout,
        n0, n1, n2, n3, n4, n5);
  }

  for (int blk = 0; blk < 3; blk++) {
    const unsigned short *Winb, *Wxb, *Woutb;
    const float *convw, *convb, *dtw, *dtb, *Alog, *Dv, *lnw, *lnb;
    int Nout;
    if (blk < 2) {
      Winb  = wWin  + (size_t)blk * 2*DId*DMdim;
      Wxb   = wWx   + (size_t)blk * 48*DId;
      Woutb = wWout + (size_t)blk * DMdim*DId;
      convw = midW_convw + (size_t)blk * DId*3;
      convb = midW_convb + (size_t)blk * DId;
      dtw   = midW_dtw   + (size_t)blk * DId*DTRd;
      dtb   = midW_dtb   + (size_t)blk * DId;
      Alog  = midA_log   + (size_t)blk * DId*DSTd;
      Dv    = midD       + (size_t)blk * DId;
      lnw   = midLNw     + (size_t)blk * DMdim;
      lnb   = midLNb     + (size_t)blk * DMdim;
      Nout  = DMdim;
    } else {
      Winb = wfWin; Wxb = wfWx; Woutb = wfWout;
      convw = finW_convw; convb = finW_convb;
      dtw = finW_dtw; dtb = finW_dtb; Alog = finA_log; Dv = finD;
      lnw = finLNw; lnb = finLNb;
      Nout = DOUTd;
    }
    const float* addsrc = (blk == 0) ? x : hbuf;
    resid_ln_kernel<<<NROWS, 256, 0, stream>>>(addsrc, res, hnb, lnw, lnb, blk == 0 ? 1 : 0);

    dim3 g1(NROWS/128, (2*DId)/64);
    gemm_bf_kernel<<<g1, 256, 0, stream>>>(hnb, Winb, ub, zb, DId, 2*DId, DMdim);

    conv_silu_kernel<<<(NROWS*DId)/256, 256, 0, stream>>>(ub, convw, convb, ucb);

    dim3 g2(NROWS/128, 1);
    gemm_bf_kernel<<<g2, 256, 0, stream>>>(ucb, Wxb, xdbl, xdbl, 48, 48, DId);

    dt_kernel<<<(NROWS*DId)/256, 256, 0, stream>>>(xdbl, dtw, dtb, dtf);

    scan1_kernel<<<Bsz*NCh*2, 256, 0, stream>>>(dtf, ucb, xdbl, Alog, hloc, Pst);
    scan2_kernel<<<64, 256, 0, stream>>>(hloc, Pst, Hinit);
    scan3_kernel<<<Bsz*NCh*2, 256, 0, stream>>>(dtf, ucb, xdbl, zb, Alog, Dv, Hinit, yb);

    float* Cout = (blk == 2) ? (float*)d_out : hbuf;
    dim3 g3(NROWS/128, (Nout + 63)/64);
    gemm_bf_kernel<<<g3, 256, 0, stream>>>(yb, Woutb, Cout, Cout, Nout, Nout, DId);
  }
}

// Round 5
// 496.976 us; speedup vs baseline: 2.1251x; 1.1072x over previous
//
#include <hip/hip_runtime.h>
#include <math.h>

#define Bsz   2
#define Lseq  4096
#define DMdim 256
#define DOUTd 128
#define DSTd  16
#define DId   512
#define DTRd  16
#define CS    32
#define NCh   128
#define NROWS (Bsz*Lseq)   // 8192
#define N2    544          // gemm2 output cols: 32 (B,C) + 512 (dt)

typedef short bf16x8 __attribute__((ext_vector_type(8)));
typedef float f32x4  __attribute__((ext_vector_type(4)));

#if __has_builtin(__builtin_amdgcn_exp2f)
#define EXP2F(x) __builtin_amdgcn_exp2f(x)
#else
#define EXP2F(x) __expf((x) * 0.69314718056f)
#endif
#define LOG2E 1.44269504f

__device__ __forceinline__ float siluf(float x) { return x / (1.f + __expf(-x)); }
__device__ __forceinline__ float softplusf(float x) {
  return fmaxf(x, 0.f) + log1pf(__expf(-fabsf(x)));
}
__device__ __forceinline__ unsigned short f2bf(float f) {
  union { float f; unsigned int u; } v; v.f = f;
  unsigned int r = v.u + 0x7fffu + ((v.u >> 16) & 1u);   // RNE
  return (unsigned short)(r >> 16);
}
__device__ __forceinline__ float bf2f(unsigned short h) {
  union { unsigned int u; float f; } v; v.u = ((unsigned int)h) << 16;
  return v.f;
}

// one-shot weight conversion: 4 segments fp32 -> bf16
__global__ __launch_bounds__(256) void convert4_kernel(
    const float* __restrict__ s0, const float* __restrict__ s1,
    const float* __restrict__ s2, const float* __restrict__ s3,
    unsigned short* __restrict__ d0, unsigned short* __restrict__ d1,
    unsigned short* __restrict__ d2, unsigned short* __restrict__ d3,
    int n0, int n1, int n2, int n3)
{
  int i = blockIdx.x * 256 + threadIdx.x;
  int c0 = n0, c1 = c0 + n1, c2 = c1 + n2, c3 = c2 + n3;
  if (i >= c3) return;
  if      (i < c0) d0[i]      = f2bf(s0[i]);
  else if (i < c1) d1[i - c0] = f2bf(s1[i - c0]);
  else if (i < c2) d2[i - c1] = f2bf(s2[i - c1]);
  else             d3[i - c2] = f2bf(s3[i - c2]);
}

// Build composed gemm2 weight W2 (bf16, N2 x 512) per layer:
//   rows 0..31  : Wx rows 16..47 (B then C)
//   rows 32..543: W_eff[d,e] = sum_r dtw[d,r]*Wx[r,e]
// blockIdx.y = layer (0,1 = mid, 2 = fin)
__global__ __launch_bounds__(256) void compose_kernel(
    const float* __restrict__ midW_x, const float* __restrict__ midW_dtw,
    const float* __restrict__ finW_x, const float* __restrict__ finW_dtw,
    unsigned short* __restrict__ W2)
{
  int lay = blockIdx.y;
  const float* Wx  = (lay < 2) ? midW_x  + (size_t)lay * 48 * DId : finW_x;
  const float* dtw = (lay < 2) ? midW_dtw + (size_t)lay * DId * 16 : finW_dtw;
  unsigned short* out = W2 + (size_t)lay * N2 * DId;
  int idx = blockIdx.x * 256 + threadIdx.x;   // N2*512 elements
  if (idx >= N2 * DId) return;
  int n = idx >> 9, e = idx & (DId - 1);
  float v;
  if (n < 32) {
    v = Wx[(16 + n) * DId + e];
  } else {
    int d = n - 32;
    v = 0.f;
    #pragma unroll
    for (int r = 0; r < 16; r++) v = fmaf(dtw[d * 16 + r], Wx[r * DId + e], v);
  }
  out[idx] = f2bf(v);
}

// res = (first ? x : res + h); hnb = bf16(LN(res)*w + b)
__global__ __launch_bounds__(256) void resid_ln_kernel(
    const float* __restrict__ addsrc, float* __restrict__ res, unsigned short* __restrict__ hnb,
    const float* __restrict__ w, const float* __restrict__ b, int first)
{
  int row = blockIdx.x;
  int t = threadIdx.x;
  size_t o = (size_t)row * DMdim + t;
  float v = first ? addsrc[o] : (res[o] + addsrc[o]);
  res[o] = v;
  float s1 = v, s2 = v * v;
  #pragma unroll
  for (int m = 32; m >= 1; m >>= 1) {
    s1 += __shfl_xor(s1, m, 64);
    s2 += __shfl_xor(s2, m, 64);
  }
  __shared__ float w1[4], w2[4];
  int wid = t >> 6, ln = t & 63;
  if (ln == 0) { w1[wid] = s1; w2[wid] = s2; }
  __syncthreads();
  float S1 = w1[0] + w1[1] + w1[2] + w1[3];
  float S2 = w2[0] + w2[1] + w2[2] + w2[3];
  float mean = S1 * (1.f / DMdim);
  float var  = S2 * (1.f / DMdim) - mean * mean;
  float r = rsqrtf(var + 1e-5f);
  hnb[o] = f2bf((v - mean) * r * w[t] + b[t]);
}

// bf16 MFMA GEMM, NT: acc[m,n] = sum_k A[m,k]*W[n,k].
// mode 0: fp32 out, split cols -> Cf0 (stride min(split,N)) / Cf1 (stride N-split)
// mode 1: bf16 out, split cols -> Cb0 / Cb1 (both stride DId)
// mode 2: n<32 -> Cf0[m*32+n] fp32; n>=32 -> Cf1[m*DId + n-32] = softplus(acc + bias2[n-32])
__global__ __launch_bounds__(256) void gemm_bf_kernel(
    const unsigned short* __restrict__ A, const unsigned short* __restrict__ W,
    float* __restrict__ Cf0, float* __restrict__ Cf1,
    unsigned short* __restrict__ Cb0, unsigned short* __restrict__ Cb1,
    const float* __restrict__ bias2,
    int split, int N, int K, int mode)
{
  __shared__ unsigned short Abuf[4][128][8];   // [kchunk][m][8k]
  __shared__ unsigned short Bbuf[4][64][8];    // [kchunk][n][8k]
  int tid = threadIdx.x;
  int bm = blockIdx.x * 128;
  int bn = blockIdx.y * 64;
  int wid = tid >> 6, lane = tid & 63;
  int wm = wid >> 1, wn = wid & 1;
  int l15 = lane & 15, kh = lane >> 4;
  int r4 = tid >> 2;   // 0..63
  int c4 = tid & 3;    // k chunk
  f32x4 acc[4][2];
  #pragma unroll
  for (int i = 0; i < 4; i++)
    #pragma unroll
    for (int j = 0; j < 2; j++)
      #pragma unroll
      for (int r = 0; r < 4; r++) acc[i][j][r] = 0.f;

  for (int k0 = 0; k0 < K; k0 += 32) {
    const unsigned short* ga  = A + (size_t)(bm + r4) * K + k0 + c4 * 8;
    const unsigned short* ga2 = A + (size_t)(bm + 64 + r4) * K + k0 + c4 * 8;
    *(bf16x8*)&Abuf[c4][r4][0]      = *(const bf16x8*)ga;
    *(bf16x8*)&Abuf[c4][64 + r4][0] = *(const bf16x8*)ga2;
    int wr = bn + r4;
    bf16x8 wv;
    #pragma unroll
    for (int e = 0; e < 8; e++) wv[e] = 0;
    if (wr < N) wv = *(const bf16x8*)(W + (size_t)wr * K + k0 + c4 * 8);
    *(bf16x8*)&Bbuf[c4][r4][0] = wv;
    __syncthreads();
    bf16x8 af[4], bfr[2];
    #pragma unroll
    for (int i = 0; i < 4; i++)
      af[i] = *(const bf16x8*)&Abuf[kh][wm * 64 + i * 16 + l15][0];
    #pragma unroll
    for (int j = 0; j < 2; j++)
      bfr[j] = *(const bf16x8*)&Bbuf[kh][wn * 32 + j * 16 + l15][0];
    #pragma unroll
    for (int i = 0; i < 4; i++)
      #pragma unroll
      for (int j = 0; j < 2; j++)
        acc[i][j] = __builtin_amdgcn_mfma_f32_16x16x32_bf16(af[i], bfr[j], acc[i][j], 0, 0, 0);
    __syncthreads();
  }
  // D layout: n = lane&15, m = (lane>>4)*4 + reg
  int mrow0 = bm + wm * 64 + (kh << 2);
  int ncol0 = bn + wn * 32 + l15;
  if (mode == 0) {
    int s0 = (split < N) ? split : N;
    int s1 = N - split;
    #pragma unroll
    for (int i = 0; i < 4; i++)
      #pragma unroll
      for (int j = 0; j < 2; j++) {
        int n = ncol0 + j * 16;
        if (n < N) {
          #pragma unroll
          for (int r = 0; r < 4; r++) {
            int m = mrow0 + i * 16 + r;
            if (n < split) Cf0[(size_t)m * s0 + n] = acc[i][j][r];
            else           Cf1[(size_t)m * s1 + (n - split)] = acc[i][j][r];
          }
        }
      }
  } else if (mode == 1) {
    #pragma unroll
    for (int i = 0; i < 4; i++)
      #pragma unroll
      for (int j = 0; j < 2; j++) {
        int n = ncol0 + j * 16;
        #pragma unroll
        for (int r = 0; r < 4; r++) {
          int m = mrow0 + i * 16 + r;
          if (n < split) Cb0[(size_t)m * DId + n] = f2bf(acc[i][j][r]);
          else           Cb1[(size_t)m * DId + (n - split)] = f2bf(acc[i][j][r]);
        }
      }
  } else {
    #pragma unroll
    for (int i = 0; i < 4; i++)
      #pragma unroll
      for (int j = 0; j < 2; j++) {
        int n = ncol0 + j * 16;
        if (n < N) {
          float bs = (n >= 32) ? bias2[n - 32] : 0.f;
          #pragma unroll
          for (int r = 0; r < 4; r++) {
            int m = mrow0 + i * 16 + r;
            if (n < 32) Cf0[(size_t)m * 32 + n] = acc[i][j][r];
            else        Cf1[(size_t)m * DId + (n - 32)] = softplusf(acc[i][j][r] + bs);
          }
        }
      }
  }
}

// ucb[bl,d] = bf16(silu(conv(ub))) — 8 d per thread, bf16 in/out
__global__ __launch_bounds__(256) void conv_silu_kernel(
    const unsigned short* __restrict__ ub, const float* __restrict__ cw,
    const float* __restrict__ cb, unsigned short* __restrict__ ucb)
{
  int idx = blockIdx.x * 256 + threadIdx.x;   // NROWS*64
  int d8 = (idx & 63) << 3;
  int bl = idx >> 6;
  int l  = bl & (Lseq - 1);
  bf16x8 u0 = *(const bf16x8*)(ub + (size_t)bl * DId + d8);
  bf16x8 u1, u2;
  #pragma unroll
  for (int e = 0; e < 8; e++) { u1[e] = 0; u2[e] = 0; }
  if (l >= 1) u1 = *(const bf16x8*)(ub + (size_t)(bl-1) * DId + d8);
  if (l >= 2) u2 = *(const bf16x8*)(ub + (size_t)(bl-2) * DId + d8);
  bf16x8 out;
  #pragma unroll
  for (int e = 0; e < 8; e++) {
    int d = d8 + e;
    float a = cb[d];
    a = fmaf(bf2f((unsigned short)u0[e]), cw[d*3+2], a);
    a = fmaf(bf2f((unsigned short)u1[e]), cw[d*3+1], a);
    a = fmaf(bf2f((unsigned short)u2[e]), cw[d*3+0], a);
    out[e] = (short)f2bf(siluf(a));
  }
  *(bf16x8*)(ucb + (size_t)bl * DId + d8) = out;
}

// pass1: thread per (b,chunk,d); h[16] regs, h0=0; chunk dt/u preloaded to regs.
__global__ __launch_bounds__(256) void scan1_kernel(
    const float* __restrict__ dtf, const unsigned short* __restrict__ ucb,
    const float* __restrict__ xdbl, const float* __restrict__ A_log,
    float* __restrict__ hloc, float* __restrict__ Pst)
{
  int tid = threadIdx.x;
  int bx = blockIdx.x;
  int dh = bx & 1, c = (bx >> 1) & (NCh - 1), b = bx >> 8;
  int d = dh * 256 + tid;
  size_t base = (size_t)b * Lseq + (size_t)c * CS;
  float A2[16];
  #pragma unroll
  for (int q = 0; q < 4; q++) {
    float4 av = *(const float4*)(A_log + d * 16 + q * 4);
    A2[q*4+0] = -__expf(av.x) * LOG2E;
    A2[q*4+1] = -__expf(av.y) * LOG2E;
    A2[q*4+2] = -__expf(av.z) * LOG2E;
    A2[q*4+3] = -__expf(av.w) * LOG2E;
  }
  // preload chunk
  float dtv[CS], uv[CS];
  const float* dp = dtf + base * DId + d;
  const unsigned short* up = ucb + base * DId + d;
  #pragma unroll
  for (int t = 0; t < CS; t++) {
    dtv[t] = dp[(size_t)t * DId];
    uv[t]  = bf2f(up[(size_t)t * DId]);
  }
  const float* Bc = xdbl + base * 32;   // wave-uniform
  float h[16];
  #pragma unroll
  for (int n = 0; n < 16; n++) h[n] = 0.f;
  float sdt = 0.f;
  #pragma unroll 4
  for (int t = 0; t < CS; t++) {
    float dt = dtv[t];
    float du = dt * uv[t];
    sdt += dt;
    #pragma unroll
    for (int q = 0; q < 4; q++) {
      float4 Bv = *(const float4*)(Bc + t * 32 + q * 4);   // uniform -> s_load
      h[q*4+0] = fmaf(EXP2F(dt * A2[q*4+0]), h[q*4+0], du * Bv.x);
      h[q*4+1] = fmaf(EXP2F(dt * A2[q*4+1]), h[q*4+1], du * Bv.y);
      h[q*4+2] = fmaf(EXP2F(dt * A2[q*4+2]), h[q*4+2], du * Bv.z);
      h[q*4+3] = fmaf(EXP2F(dt * A2[q*4+3]), h[q*4+3], du * Bv.w);
    }
  }
  size_t so = (((size_t)(b * NCh + c) * DId) + d) * 16;
  #pragma unroll
  for (int q = 0; q < 4; q++) {
    float4 hv, pv;
    hv.x = h[q*4+0]; hv.y = h[q*4+1]; hv.z = h[q*4+2]; hv.w = h[q*4+3];
    pv.x = EXP2F(sdt * A2[q*4+0]);
    pv.y = EXP2F(sdt * A2[q*4+1]);
    pv.z = EXP2F(sdt * A2[q*4+2]);
    pv.w = EXP2F(sdt * A2[q*4+3]);
    *(float4*)(hloc + so + q * 4) = hv;
    *(float4*)(Pst  + so + q * 4) = pv;
  }
}

// pass2: sequential scan over chunks; store incoming state per chunk
__global__ __launch_bounds__(256) void scan2_kernel(
    const float* __restrict__ hloc, const float* __restrict__ Pst,
    float* __restrict__ Hinit)
{
  int idx = blockIdx.x * 256 + threadIdx.x;  // B*DI*DST = 16384
  int dn = idx & (DId * DSTd - 1);
  int b  = idx >> 13;
  float H = 0.f;
  #pragma unroll 4
  for (int c = 0; c < NCh; c++) {
    size_t o = ((size_t)(b * NCh + c)) * (DId * DSTd) + dn;
    Hinit[o] = H;
    H = fmaf(Pst[o], H, hloc[o]);
  }
}

// pass3: rerun with correct h0; y = C.h; yb = bf16((y+u*D)*silu(z))
__global__ __launch_bounds__(256) void scan3_kernel(
    const float* __restrict__ dtf, const unsigned short* __restrict__ ucb,
    const float* __restrict__ xdbl, const unsigned short* __restrict__ zb,
    const float* __restrict__ A_log, const float* __restrict__ Dv,
    const float* __restrict__ Hinit, unsigned short* __restrict__ yb)
{
  int tid = threadIdx.x;
  int bx = blockIdx.x;
  int dh = bx & 1, c = (bx >> 1) & (NCh - 1), b = bx >> 8;
  int d = dh * 256 + tid;
  size_t base = (size_t)b * Lseq + (size_t)c * CS;
  float A2[16];
  #pragma unroll
  for (int q = 0; q < 4; q++) {
    float4 av = *(const float4*)(A_log + d * 16 + q * 4);
    A2[q*4+0] = -__expf(av.x) * LOG2E;
    A2[q*4+1] = -__expf(av.y) * LOG2E;
    A2[q*4+2] = -__expf(av.z) * LOG2E;
    A2[q*4+3] = -__expf(av.w) * LOG2E;
  }
  // preload chunk
  float dtv[CS], uv[CS], zv[CS];
  const float* dp = dtf + base * DId + d;
  const unsigned short* up = ucb + base * DId + d;
  const unsigned short* zp = zb + base * DId + d;
  #pragma unroll
  for (int t = 0; t < CS; t++) {
    dtv[t] = dp[(size_t)t * DId];
    uv[t]  = bf2f(up[(size_t)t * DId]);
    zv[t]  = bf2f(zp[(size_t)t * DId]);
  }
  const float* Bc = xdbl + base * 32;
  size_t so = (((size_t)(b * NCh + c) * DId) + d) * 16;
  float h[16];
  #pragma unroll
  for (int q = 0; q < 4; q++) {
    float4 hv = *(const float4*)(Hinit + so + q * 4);
    h[q*4+0] = hv.x; h[q*4+1] = hv.y; h[q*4+2] = hv.z; h[q*4+3] = hv.w;
  }
  float Dd = Dv[d];
  #pragma unroll 4
  for (int t = 0; t < CS; t++) {
    float dt = dtv[t];
    float u  = uv[t];
    float du = dt * u;
    float y = 0.f;
    #pragma unroll
    for (int q = 0; q < 4; q++) {
      float4 Bv = *(const float4*)(Bc + t * 32 + q * 4);        // uniform
      float4 Cv = *(const float4*)(Bc + t * 32 + 16 + q * 4);   // uniform
      h[q*4+0] = fmaf(EXP2F(dt * A2[q*4+0]), h[q*4+0], du * Bv.x);
      h[q*4+1] = fmaf(EXP2F(dt * A2[q*4+1]), h[q*4+1], du * Bv.y);
      h[q*4+2] = fmaf(EXP2F(dt * A2[q*4+2]), h[q*4+2], du * Bv.z);
      h[q*4+3] = fmaf(EXP2F(dt * A2[q*4+3]), h[q*4+3], du * Bv.w);
      y = fmaf(h[q*4+0], Cv.x, y);
      y = fmaf(h[q*4+1], Cv.y, y);
      y = fmaf(h[q*4+2], Cv.z, y);
      y = fmaf(h[q*4+3], Cv.w, y);
    }
    yb[(base + t) * DId + d] = f2bf((y + u * Dd) * siluf(zv[t]));
  }
}

extern "C" void kernel_launch(void* const* d_in, const int* in_sizes, int n_in,
                              void* d_out, int out_size, void* d_ws, size_t ws_size,
                              hipStream_t stream)
{
  const float* x          = (const float*)d_in[0];
  const float* midW_in    = (const float*)d_in[1];
  const float* midW_convw = (const float*)d_in[2];
  const float* midW_convb = (const float*)d_in[3];
  const float* midW_x     = (const float*)d_in[4];
  const float* midW_dtw   = (const float*)d_in[5];
  const float* midW_dtb   = (const float*)d_in[6];
  const float* midA_log   = (const float*)d_in[7];
  const float* midD       = (const float*)d_in[8];
  const float* midW_out   = (const float*)d_in[9];
  const float* midLNw     = (const float*)d_in[10];
  const float* midLNb     = (const float*)d_in[11];
  const float* finW_in    = (const float*)d_in[12];
  const float* finW_convw = (const float*)d_in[13];
  const float* finW_convb = (const float*)d_in[14];
  const float* finW_x     = (const float*)d_in[15];
  const float* finW_dtw   = (const float*)d_in[16];
  const float* finW_dtb   = (const float*)d_in[17];
  const float* finA_log   = (const float*)d_in[18];
  const float* finD       = (const float*)d_in[19];
  const float* finW_out   = (const float*)d_in[20];
  const float* finLNw     = (const float*)d_in[21];
  const float* finLNb     = (const float*)d_in[22];

  // workspace layout: fp32 ~58 MB + bf16 ~41 MB = ~99 MB
  float* ws    = (float*)d_ws;
  float* res   = ws;                    // 2,097,152
  float* xdbl  = res   + 2097152;       // 262,144 (B,C only; stride 32)
  float* hloc  = xdbl  + 262144;        // 2,097,152
  float* Pst   = hloc  + 2097152;       // 2,097,152
  float* Hinit = Pst   + 2097152;       // 2,097,152
  float* hbuf  = Hinit + 2097152;       // 2,097,152
  float* dtf   = hbuf  + 2097152;       // 4,194,304
  unsigned short* us = (unsigned short*)(dtf + 4194304);
  unsigned short* hnb   = us;                 // 2,097,152
  unsigned short* ub    = hnb  + 2097152;     // 4,194,304
  unsigned short* zbuf  = ub   + 4194304;     // 4,194,304
  unsigned short* ucb   = zbuf + 4194304;     // 4,194,304
  unsigned short* yb    = ucb  + 4194304;     // 4,194,304
  unsigned short* wWin  = yb   + 4194304;     // 524,288 (2 layers)
  unsigned short* wWout = wWin + 524288;      // 262,144
  unsigned short* wfWin = wWout+ 262144;      // 262,144
  unsigned short* wfWout= wfWin+ 262144;      // 65,536
  unsigned short* wW2   = wfWout + 65536;     // 3 * 544*512 = 835,584

  {
    int n0 = 524288, n1 = 262144, n2 = 262144, n3 = 65536;
    int tot = n0 + n1 + n2 + n3;
    convert4_kernel<<<(tot + 255) / 256, 256, 0, stream>>>(
        midW_in, midW_out, finW_in, finW_out,
        wWin, wWout, wfWin, wfWout, n0, n1, n2, n3);
    dim3 gc((N2 * DId + 255) / 256, 3);
    compose_kernel<<<gc, 256, 0, stream>>>(midW_x, midW_dtw, finW_x, finW_dtw, wW2);
  }

  for (int blk = 0; blk < 3; blk++) {
    const unsigned short *Winb, *W2b, *Woutb;
    const float *convw, *convb, *dtb, *Alog, *Dv, *lnw, *lnb;
    int Nout;
    if (blk < 2) {
      Winb  = wWin  + (size_t)blk * 2*DId*DMdim;
      W2b   = wW2   + (size_t)blk * N2*DId;
      Woutb = wWout + (size_t)blk * DMdim*DId;
      convw = midW_convw + (size_t)blk * DId*3;
      convb = midW_convb + (size_t)blk * DId;
      dtb   = midW_dtb   + (size_t)blk * DId;
      Alog  = midA_log   + (size_t)blk * DId*DSTd;
      Dv    = midD       + (size_t)blk * DId;
      lnw   = midLNw     + (size_t)blk * DMdim;
      lnb   = midLNb     + (size_t)blk * DMdim;
      Nout  = DMdim;
    } else {
      Winb = wfWin; W2b = wW2 + (size_t)2 * N2*DId; Woutb = wfWout;
      convw = finW_convw; convb = finW_convb;
      dtb = finW_dtb; Alog = finA_log; Dv = finD;
      lnw = finLNw; lnb = finLNb;
      Nout = DOUTd;
    }
    const float* addsrc = (blk == 0) ? x : hbuf;
    resid_ln_kernel<<<NROWS, 256, 0, stream>>>(addsrc, res, hnb, lnw, lnb, blk == 0 ? 1 : 0);

    // gemm1: u/z halves as bf16
    dim3 g1(NROWS/128, (2*DId)/64);
    gemm_bf_kernel<<<g1, 256, 0, stream>>>(hnb, Winb, nullptr, nullptr, ub, zbuf,
                                           nullptr, DId, 2*DId, DMdim, 1);

    conv_silu_kernel<<<(NROWS*64)/256, 256, 0, stream>>>(ub, convw, convb, ucb);

    // gemm2: [B,C | dt] composed; softplus+bias epilogue writes dtf
    dim3 g2(NROWS/128, (N2 + 63)/64);
    gemm_bf_kernel<<<g2, 256, 0, stream>>>(ucb, W2b, xdbl, dtf, nullptr, nullptr,
                                           dtb, 32, N2, DId, 2);

    scan1_kernel<<<Bsz*NCh*2, 256, 0, stream>>>(dtf, ucb, xdbl, Alog, hloc, Pst);
    scan2_kernel<<<64, 256, 0, stream>>>(hloc, Pst, Hinit);
    scan3_kernel<<<Bsz*NCh*2, 256, 0, stream>>>(dtf, ucb, xdbl, zbuf, Alog, Dv, Hinit, yb);

    float* Cout = (blk == 2) ? (float*)d_out : hbuf;
    dim3 g3(NROWS/128, (Nout + 63)/64);
    gemm_bf_kernel<<<g3, 256, 0, stream>>>(yb, Woutb, Cout, Cout, nullptr, nullptr,
                                           nullptr, Nout, Nout, DId, 0);
  }
}